// Round 1
// baseline (221.697 us; speedup 1.0000x reference)
//
#include <hip/hip_runtime.h>

#define NCOLS 1024         // N fixed at 1024 per reference setup
#define ROWS_PER_WAVE 4    // persistent wave: 4 rows, software-pipelined

// Native clang vector type — accepted by __builtin_nontemporal_load/store.
typedef float vfloat4 __attribute__((ext_vector_type(4)));

__device__ __forceinline__ const vfloat4* row_src(const float* __restrict__ a0,
                                                  const float* __restrict__ a1,
                                                  int row, int rows_per_input) {
    // Wave-uniform branch (all lanes share `row`).
    const float* s = (row < rows_per_input)
        ? a0 + (size_t)row * NCOLS
        : a1 + (size_t)(row - rows_per_input) * NCOLS;
    return reinterpret_cast<const vfloat4*>(s);
}

__device__ __forceinline__ float row_sum(vfloat4 v0, vfloat4 v1, vfloat4 v2, vfloat4 v3) {
    // Pairwise per-lane partial (16 values), then 6-step butterfly so every
    // lane ends with the full row sum (no broadcast needed).
    float s = ((v0.x + v0.y) + (v0.z + v0.w)) + ((v1.x + v1.y) + (v1.z + v1.w))
            + ((v2.x + v2.y) + (v2.z + v2.w)) + ((v3.x + v3.y) + (v3.z + v3.w));
#pragma unroll
    for (int off = 32; off > 0; off >>= 1)
        s += __shfl_xor(s, off, 64);
    return s;
}

// Persistent-wave version: each wave owns ROWS_PER_WAVE consecutive rows and
// prefetches row i+1 while reducing/scaling/storing row i. Program order puts
// the next-row loads BEFORE the current-row consumption, so the compiler waits
// with s_waitcnt vmcnt(8) (next loads + prev stores stay in flight) instead of
// draining to vmcnt(0) per row — HBM latency hides under the reduce+store.
__global__ __launch_bounds__(256) void Normalizer_row_kernel(
    const float* __restrict__ a0, const float* __restrict__ a1,
    float* __restrict__ out, int rows_per_input) {
    const int lane  = threadIdx.x & 63;
    const int gwave = (blockIdx.x * 256 + threadIdx.x) >> 6;  // global wave id
    int row = gwave * ROWS_PER_WAVE;                          // chunked: 16 KiB/wave

    // Prologue: issue row 0's loads.
    const vfloat4* sp = row_src(a0, a1, row, rows_per_input);
    vfloat4 c0 = __builtin_nontemporal_load(&sp[lane]);
    vfloat4 c1 = __builtin_nontemporal_load(&sp[lane + 64]);
    vfloat4 c2 = __builtin_nontemporal_load(&sp[lane + 128]);
    vfloat4 c3 = __builtin_nontemporal_load(&sp[lane + 192]);

#pragma unroll
    for (int i = 0; i < ROWS_PER_WAVE; ++i) {
        // Prefetch next row (fully unrolled -> compile-time guard, named regs,
        // no runtime-indexed arrays: everything stays in VGPRs).
        vfloat4 n0, n1, n2, n3;
        if (i + 1 < ROWS_PER_WAVE) {
            const vfloat4* np = row_src(a0, a1, row + 1, rows_per_input);
            n0 = __builtin_nontemporal_load(&np[lane]);
            n1 = __builtin_nontemporal_load(&np[lane + 64]);
            n2 = __builtin_nontemporal_load(&np[lane + 128]);
            n3 = __builtin_nontemporal_load(&np[lane + 192]);
        }

        // Consume current row (compiler waits only on its 4 loads; the 4
        // prefetch loads and previous iteration's 4 stores remain in flight).
        float s = row_sum(c0, c1, c2, c3);
        float inv = 1.0f / s;
        if (!isfinite(inv)) inv = 0.0f;  // nan/inf -> 0 per reference

        // Output is the two normalized tensors concatenated -> row-major dst.
        vfloat4* dp = reinterpret_cast<vfloat4*>(out + (size_t)row * NCOLS);
        __builtin_nontemporal_store(c0 * inv, &dp[lane]);
        __builtin_nontemporal_store(c1 * inv, &dp[lane + 64]);
        __builtin_nontemporal_store(c2 * inv, &dp[lane + 128]);
        __builtin_nontemporal_store(c3 * inv, &dp[lane + 192]);

        if (i + 1 < ROWS_PER_WAVE) {
            c0 = n0; c1 = n1; c2 = n2; c3 = n3;
            ++row;
        }
    }
}

extern "C" void kernel_launch(void* const* d_in, const int* in_sizes, int n_in,
                              void* d_out, int out_size, void* d_ws, size_t ws_size,
                              hipStream_t stream) {
    const float* a0 = (const float*)d_in[0];
    const float* a1 = (const float*)d_in[1];
    float* out = (float*)d_out;

    const int rows_per_input = in_sizes[0] / NCOLS;   // 16 * 1024 = 16384
    const int total_rows = 2 * rows_per_input;        // 32768
    // 4 waves/block x ROWS_PER_WAVE rows/wave = 16 rows per block.
    const int blocks = total_rows / (4 * ROWS_PER_WAVE);  // 2048 = 8 blocks/CU

    Normalizer_row_kernel<<<blocks, 256, 0, stream>>>(a0, a1, out, rows_per_input);
}